// Round 1
// 227.024 us; speedup vs baseline: 1.3352x; 1.3352x over previous
//
#include <hip/hip_runtime.h>
#include <math.h>

// Problem constants (B=4, S=4096, D=2048, E=64, K=2)
#define BS_TOT 16384
#define DDIM   2048
#define NEXP   64
#define TOPK   2

#define RPB    32                  // rows per block
#define NWV    8                   // waves per block (K-split across waves)
#define KCHUNK (DDIM / NWV)        // 256 d per wave
#define KTILE  32                  // MFMA K per step
#define NKT    (KCHUNK / KTILE)    // 8 K-tiles per wave
#define PADE   68                  // pbuf row pad: (lane>>4)*272 %128B -> 2-way banks only

typedef _Float16 half8   __attribute__((ext_vector_type(8)));
typedef float    floatx4 __attribute__((ext_vector_type(4)));

// ---------------------------------------------------------------------------
// Pre-pass: W [D][E] fp32  ->  W^T hi/lo fp16, lo scaled by 2048 so W-lo
// values (~1e-5) stay fp16-normal (subnormal MFMA flush hazard avoided).
// 512 KB in d_ws; L2-resident thereafter.
// ---------------------------------------------------------------------------
__global__ __launch_bounds__(256)
void wsplit_kernel(const float* __restrict__ W, _Float16* __restrict__ whi,
                   _Float16* __restrict__ wlo)
{
    const int idx = blockIdx.x * 256 + threadIdx.x;  // 16384 threads, exact fit
    const int e   = idx >> 8;                        // 0..63
    const int d0  = (idx & 255) * 8;                 // 0..2040
    half8 vh, vl;
#pragma unroll
    for (int j = 0; j < 8; ++j) {
        const float v = W[(size_t)(d0 + j) * NEXP + e];
        const _Float16 h = (_Float16)v;
        vh[j] = h;
        vl[j] = (_Float16)((v - (float)h) * 2048.0f);
    }
    *(half8*)(whi + (size_t)e * DDIM + d0) = vh;     // 16B coalesced-ish stores
    *(half8*)(wlo + (size_t)e * DDIM + d0) = vl;
}

// ---------------------------------------------------------------------------
// Main: 512 blocks x 512 thr. Block owns 32 rows; wave wv owns K-chunk
// [wv*256, wv*256+256). Barrier-free MFMA main loop, regs only:
//   A (x rows): per-lane 8 fp32 contiguous k -> in-reg split to f16 hi/lo_s.
//     frag layout 16x16x32: A row = lane&15, k = (lane>>4)*8 + j.
//   B (W^T):    col = lane&15 (expert), same k slice; 16B/lane from L2.
//   3-pass: hi*hi -> acc ; lo_s*hi + hi*lo_s -> acc_lo ; out = acc+acc_lo/2048.
// Epilogue: K-reduce via LDS, then proven softmax/top-2 (unchanged logic).
// ---------------------------------------------------------------------------
__global__ __launch_bounds__(512)
void router_mfma(const float* __restrict__ x, const _Float16* __restrict__ whi,
                 const _Float16* __restrict__ wlo, const float* __restrict__ bias,
                 const float* __restrict__ noise, float* __restrict__ out)
{
    __shared__ float pbuf[NWV][RPB][PADE];   // 69,632 B

    const int tid  = threadIdx.x;
    const int lane = tid & 63;
    const int wv   = __builtin_amdgcn_readfirstlane(tid >> 6);  // 0..7
    const int row0 = blockIdx.x * RPB;
    const int rr   = lane & 15;   // A-row / B-col within 16-tile
    const int kg   = lane >> 4;   // k-group 0..3 -> k offset kg*8

    floatx4 acc[2][4];    // [m-tile][e-tile] hi*hi
    floatx4 accl[2][4];   // scaled-lo cross terms
#pragma unroll
    for (int m = 0; m < 2; ++m)
#pragma unroll
        for (int e = 0; e < 4; ++e) {
            acc[m][e]  = (floatx4){0.f, 0.f, 0.f, 0.f};
            accl[m][e] = (floatx4){0.f, 0.f, 0.f, 0.f};
        }

    const int kb = wv * KCHUNK;
    const float* xp0 = x + (size_t)(row0 + rr) * DDIM + kb + kg * 8;   // m-tile 0
    const float* xp1 = xp0 + (size_t)16 * DDIM;                        // m-tile 1
    const _Float16* wph = whi + (size_t)rr * DDIM + kb + kg * 8;
    const _Float16* wpl = wlo + (size_t)rr * DDIM + kb + kg * 8;

#pragma unroll 1
    for (int t = 0; t < NKT; ++t) {
        const int ko = t * KTILE;
        // ---- A fragments: fp32 loads (32B/lane/m-tile), in-reg hi/lo split
        const floatx4 xa0 = *(const floatx4*)(xp0 + ko);
        const floatx4 xb0 = *(const floatx4*)(xp0 + ko + 4);
        const floatx4 xa1 = *(const floatx4*)(xp1 + ko);
        const floatx4 xb1 = *(const floatx4*)(xp1 + ko + 4);
        half8 ah0, al0, ah1, al1;
#pragma unroll
        for (int i = 0; i < 4; ++i) {
            _Float16 h;
            h = (_Float16)xa0[i]; ah0[i]     = h; al0[i]     = (_Float16)((xa0[i] - (float)h) * 2048.0f);
            h = (_Float16)xb0[i]; ah0[4 + i] = h; al0[4 + i] = (_Float16)((xb0[i] - (float)h) * 2048.0f);
            h = (_Float16)xa1[i]; ah1[i]     = h; al1[i]     = (_Float16)((xa1[i] - (float)h) * 2048.0f);
            h = (_Float16)xb1[i]; ah1[4 + i] = h; al1[4 + i] = (_Float16)((xb1[i] - (float)h) * 2048.0f);
        }
        // ---- B fragments straight from L2-resident W^T; 6 MFMA per e-tile
#pragma unroll
        for (int et = 0; et < 4; ++et) {
            const size_t eo = (size_t)et * 16 * DDIM + ko;
            const half8 bh = *(const half8*)(wph + eo);
            const half8 bl = *(const half8*)(wpl + eo);
            acc[0][et]  = __builtin_amdgcn_mfma_f32_16x16x32_f16(ah0, bh, acc[0][et], 0, 0, 0);
            acc[1][et]  = __builtin_amdgcn_mfma_f32_16x16x32_f16(ah1, bh, acc[1][et], 0, 0, 0);
            accl[0][et] = __builtin_amdgcn_mfma_f32_16x16x32_f16(al0, bh, accl[0][et], 0, 0, 0);
            accl[1][et] = __builtin_amdgcn_mfma_f32_16x16x32_f16(al1, bh, accl[1][et], 0, 0, 0);
            accl[0][et] = __builtin_amdgcn_mfma_f32_16x16x32_f16(ah0, bl, accl[0][et], 0, 0, 0);
            accl[1][et] = __builtin_amdgcn_mfma_f32_16x16x32_f16(ah1, bl, accl[1][et], 0, 0, 0);
        }
    }

    // ---- combine passes, deposit per-wave partials (D: row=(lane>>4)*4+r, col=lane&15)
#pragma unroll
    for (int mt = 0; mt < 2; ++mt)
#pragma unroll
        for (int et = 0; et < 4; ++et) {
            const floatx4 v  = acc[mt][et];
            const floatx4 vl = accl[mt][et];
#pragma unroll
            for (int r = 0; r < 4; ++r)
                pbuf[wv][mt * 16 + kg * 4 + r][et * 16 + rr] =
                    v[r] + vl[r] * (1.0f / 2048.0f);
        }
    __syncthreads();

    // ---------------- epilogue: 4 rows per wave, all cross-lane ------------
    const float blane = bias[lane];
    float* const scores_out = out + 2 * BS_TOT * TOPK;
    float* const iout       = out + BS_TOT * TOPK;

#pragma unroll
    for (int j = 0; j < RPB / NWV; ++j) {
        const int rl = wv * (RPB / NWV) + j;
        const int r2 = row0 + rl;
        float v = 0.0f;
#pragma unroll
        for (int p = 0; p < NWV; ++p) v += pbuf[p][rl][lane];   // K-reduce
        v += blane + 0.1f * noise[(size_t)r2 * NEXP + lane];

        float m = v;
#pragma unroll
        for (int off = 1; off < 64; off <<= 1) m = fmaxf(m, __shfl_xor(m, off));
        const float p = __expf(v - m);
        float s = p;
#pragma unroll
        for (int off = 1; off < 64; off <<= 1) s += __shfl_xor(s, off);
        const float sc = p * (1.0f / s);

        scores_out[(size_t)r2 * NEXP + lane] = sc;   // 256B coalesced

        // top-2 across 64 lanes on logits (order-identical to scores),
        // ties -> lower index (matches jax.lax.top_k).
        float a1 = v, a2 = -INFINITY;
        int   i1 = lane, i2 = 0x7fffffff;
#pragma unroll
        for (int off = 1; off < 64; off <<= 1) {
            const float o1 = __shfl_xor(a1, off), o2 = __shfl_xor(a2, off);
            const int  oi1 = __shfl_xor(i1, off), oi2 = __shfl_xor(i2, off);
            if (o1 > a1 || (o1 == a1 && oi1 < i1)) {
                if (a1 > o2 || (a1 == o2 && i1 < oi2)) { a2 = a1; i2 = i1; }
                else                                   { a2 = o2; i2 = oi2; }
                a1 = o1; i1 = oi1;
            } else {
                if (o1 > a2 || (o1 == a2 && oi1 < i2)) { a2 = o1; i2 = oi1; }
            }
        }
        const float s1 = __shfl(sc, i1);   // bitwise == scores entries
        const float s2 = __shfl(sc, i2);
        if (lane == 0) {
            out[(size_t)r2 * TOPK + 0]  = s1;
            out[(size_t)r2 * TOPK + 1]  = s2;
            iout[(size_t)r2 * TOPK + 0] = (float)i1;
            iout[(size_t)r2 * TOPK + 1] = (float)i2;
        }
    }
}

extern "C" void kernel_launch(void* const* d_in, const int* in_sizes, int n_in,
                              void* d_out, int out_size, void* d_ws, size_t ws_size,
                              hipStream_t stream)
{
    const float* x     = (const float*)d_in[0];
    const float* W     = (const float*)d_in[1];
    const float* bias  = (const float*)d_in[2];
    const float* noise = (const float*)d_in[3];
    float* out = (float*)d_out;
    (void)in_sizes; (void)n_in; (void)out_size; (void)ws_size;

    _Float16* whi = (_Float16*)d_ws;             // 256 KB
    _Float16* wlo = whi + (size_t)NEXP * DDIM;   // 256 KB  (ws needs 512 KB)

    hipLaunchKernelGGL(wsplit_kernel, dim3(NEXP * DDIM / 8 / 256), dim3(256), 0,
                       stream, W, whi, wlo);
    hipLaunchKernelGGL(router_mfma, dim3(BS_TOT / RPB), dim3(512), 0, stream,
                       x, whi, wlo, bias, noise, out);
}

// Round 3
// 225.810 us; speedup vs baseline: 1.3423x; 1.0054x over previous
//
#include <hip/hip_runtime.h>
#include <math.h>

// Problem constants (B=4, S=4096, D=2048, E=64, K=2)
#define BS_TOT 16384
#define DDIM   2048
#define NEXP   64
#define TOPK   2

#define RPB    32                  // rows per block
#define NWV    8                   // waves per block (K-split across waves)
#define KCHUNK (DDIM / NWV)        // 256 d per wave
#define KTILE  32                  // MFMA K per step
#define NKT    (KCHUNK / KTILE)    // 8 K-tiles per wave
#define PADE   68                  // pbuf row pad

typedef _Float16 half8   __attribute__((ext_vector_type(8)));
typedef float    floatx4 __attribute__((ext_vector_type(4)));

// ---------------------------------------------------------------------------
// Pre-pass: W [D][E] fp32 -> interleaved W^T hi|lo fp16 (lo scaled by 2048).
// Layout: wint[((e*256 + g)*16)]: halfs 0..7 = hi(k=g*8..g*8+7), 8..15 = lo.
// One 32B chunk per (e, 8k) -> bh/bl of a fragment share a cache line.
// 512 KB in d_ws; L2-resident thereafter.
// ---------------------------------------------------------------------------
__global__ __launch_bounds__(256)
void wsplit_kernel(const float* __restrict__ W, _Float16* __restrict__ wint)
{
    const int e = blockIdx.x;        // 0..63
    const int g = threadIdx.x;       // 0..255 (k-group of 8)
    half8 vh, vl;
#pragma unroll
    for (int j = 0; j < 8; ++j) {
        const float v = W[(size_t)(g * 8 + j) * NEXP + e];
        const _Float16 h = (_Float16)v;
        vh[j] = h;
        vl[j] = (_Float16)((v - (float)h) * 2048.0f);
    }
    _Float16* p = wint + ((size_t)e * 256 + g) * 16;
    *(half8*)(p)     = vh;           // 32B contiguous per thread, coalesced
    *(half8*)(p + 8) = vl;
}

// ---------------------------------------------------------------------------
// Main: 512 blocks x 512 thr. Block owns 32 rows; wave wv owns K-chunk
// [wv*256, wv*256+256). Software-pipelined, barrier-free MFMA main loop:
//   A (x rows) prefetched 2 tiles deep, B (W^T int) 1 tile deep -> ~16KB
//   in flight per wave; vmcnt waits become counted, not drain-to-0.
//   frag layout 16x16x32: A row = lane&15, k = (lane>>4)*8 + j; B col=lane&15.
//   3-pass: hi*hi -> acc ; lo_s*hi + hi*lo_s -> acc_lo ; out = acc+acc_lo/2048.
// Epilogue: K-reduce via LDS, then proven softmax/top-2 (unchanged logic).
// ---------------------------------------------------------------------------
__global__ __launch_bounds__(512)
void router_mfma(const float* __restrict__ x, const _Float16* __restrict__ wint,
                 const float* __restrict__ bias, const float* __restrict__ noise,
                 float* __restrict__ out)
{
    __shared__ float pbuf[NWV][RPB][PADE];   // 69,632 B

    const int tid  = threadIdx.x;
    const int lane = tid & 63;
    const int wv   = __builtin_amdgcn_readfirstlane(tid >> 6);  // 0..7
    const int row0 = blockIdx.x * RPB;
    const int rr   = lane & 15;   // A-row / B-col within 16-tile
    const int kg   = lane >> 4;   // k-group 0..3 -> k offset kg*8

    floatx4 acc[2][4];    // [m-tile][e-tile] hi*hi
    floatx4 accl[2][4];   // scaled-lo cross terms
#pragma unroll
    for (int m = 0; m < 2; ++m)
#pragma unroll
        for (int e = 0; e < 4; ++e) {
            acc[m][e]  = (floatx4){0.f, 0.f, 0.f, 0.f};
            accl[m][e] = (floatx4){0.f, 0.f, 0.f, 0.f};
        }

    const int kb = wv * KCHUNK;
    const float* xp0 = x + (size_t)(row0 + rr) * DDIM + kb + kg * 8;   // m-tile 0
    const float* xp1 = xp0 + (size_t)16 * DDIM;                        // m-tile 1
    // B base: e=rr, g = kb/8 + kg; per et add et*16 rows (65536 halfs),
    // per tile add 4 groups (64 halfs).
    const _Float16* wib = wint + ((size_t)rr * 256 + (kb >> 3) + kg) * 16;

    floatx4 gA[2][4];              // 2-deep A prefetch
    half8   gh[2][4], gl[2][4];    // 1-deep B prefetch (cur/next)

#define LOADA(t, s) do { \
        gA[s][0] = *(const floatx4*)(xp0 + (t) * KTILE);     \
        gA[s][1] = *(const floatx4*)(xp0 + (t) * KTILE + 4); \
        gA[s][2] = *(const floatx4*)(xp1 + (t) * KTILE);     \
        gA[s][3] = *(const floatx4*)(xp1 + (t) * KTILE + 4); } while (0)

#define LOADB(t, s) do { \
        _Pragma("unroll") \
        for (int et = 0; et < 4; ++et) { \
            const _Float16* bp = wib + et * 65536 + (t) * 64; \
            gh[s][et] = *(const half8*)(bp);                  \
            gl[s][et] = *(const half8*)(bp + 8); } } while (0)

    // pipeline prologue: A(0), A(1), B(0) in flight
    LOADA(0, 0);
    LOADA(1, 1);
    LOADB(0, 0);

#pragma unroll
    for (int t = 0; t < NKT; ++t) {
        const int cur = t & 1, nxt = cur ^ 1;
        // ---- cvt A(t): fp32 -> f16 hi / scaled-lo (waits only A(t) loads)
        half8 ah0, al0, ah1, al1;
#pragma unroll
        for (int i = 0; i < 4; ++i) {
            _Float16 h;
            h = (_Float16)gA[cur][0][i]; ah0[i]     = h; al0[i]     = (_Float16)((gA[cur][0][i] - (float)h) * 2048.0f);
            h = (_Float16)gA[cur][1][i]; ah0[4 + i] = h; al0[4 + i] = (_Float16)((gA[cur][1][i] - (float)h) * 2048.0f);
            h = (_Float16)gA[cur][2][i]; ah1[i]     = h; al1[i]     = (_Float16)((gA[cur][2][i] - (float)h) * 2048.0f);
            h = (_Float16)gA[cur][3][i]; ah1[4 + i] = h; al1[4 + i] = (_Float16)((gA[cur][3][i] - (float)h) * 2048.0f);
        }
        // ---- keep the pipe full: issue A(t+2), B(t+1) before the MFMAs
        if (t + 2 < NKT) LOADA(t + 2, cur);   // slot freed by cvt above
        if (t + 1 < NKT) LOADB(t + 1, nxt);
        // ---- 24 MFMAs on tile t (B(t) was issued one tile ago)
#pragma unroll
        for (int et = 0; et < 4; ++et) {
            const half8 bh = gh[cur][et];
            const half8 bl = gl[cur][et];
            acc[0][et]  = __builtin_amdgcn_mfma_f32_16x16x32_f16(ah0, bh, acc[0][et], 0, 0, 0);
            acc[1][et]  = __builtin_amdgcn_mfma_f32_16x16x32_f16(ah1, bh, acc[1][et], 0, 0, 0);
            accl[0][et] = __builtin_amdgcn_mfma_f32_16x16x32_f16(al0, bh, accl[0][et], 0, 0, 0);
            accl[1][et] = __builtin_amdgcn_mfma_f32_16x16x32_f16(al1, bh, accl[1][et], 0, 0, 0);
            accl[0][et] = __builtin_amdgcn_mfma_f32_16x16x32_f16(ah0, bl, accl[0][et], 0, 0, 0);
            accl[1][et] = __builtin_amdgcn_mfma_f32_16x16x32_f16(ah1, bl, accl[1][et], 0, 0, 0);
        }
    }
#undef LOADA
#undef LOADB

    // ---- combine passes, deposit per-wave partials (D: row=(lane>>4)*4+r, col=lane&15)
#pragma unroll
    for (int mt = 0; mt < 2; ++mt)
#pragma unroll
        for (int et = 0; et < 4; ++et) {
            const floatx4 v  = acc[mt][et];
            const floatx4 vl = accl[mt][et];
#pragma unroll
            for (int r = 0; r < 4; ++r)
                pbuf[wv][mt * 16 + kg * 4 + r][et * 16 + rr] =
                    v[r] + vl[r] * (1.0f / 2048.0f);
        }
    __syncthreads();

    // ---------------- epilogue: 4 rows per wave, all cross-lane ------------
    const float blane = bias[lane];
    float* const scores_out = out + 2 * BS_TOT * TOPK;
    float* const iout       = out + BS_TOT * TOPK;

#pragma unroll
    for (int j = 0; j < RPB / NWV; ++j) {
        const int rl = wv * (RPB / NWV) + j;
        const int r2 = row0 + rl;
        float v = 0.0f;
#pragma unroll
        for (int p = 0; p < NWV; ++p) v += pbuf[p][rl][lane];   // K-reduce
        v += blane + 0.1f * noise[(size_t)r2 * NEXP + lane];

        float m = v;
#pragma unroll
        for (int off = 1; off < 64; off <<= 1) m = fmaxf(m, __shfl_xor(m, off));
        const float p = __expf(v - m);
        float s = p;
#pragma unroll
        for (int off = 1; off < 64; off <<= 1) s += __shfl_xor(s, off);
        const float sc = p * (1.0f / s);

        scores_out[(size_t)r2 * NEXP + lane] = sc;   // 256B coalesced

        // top-2 across 64 lanes on logits (order-identical to scores),
        // ties -> lower index (matches jax.lax.top_k).
        float a1 = v, a2 = -INFINITY;
        int   i1 = lane, i2 = 0x7fffffff;
#pragma unroll
        for (int off = 1; off < 64; off <<= 1) {
            const float o1 = __shfl_xor(a1, off), o2 = __shfl_xor(a2, off);
            const int  oi1 = __shfl_xor(i1, off), oi2 = __shfl_xor(i2, off);
            if (o1 > a1 || (o1 == a1 && oi1 < i1)) {
                if (a1 > o2 || (a1 == o2 && i1 < oi2)) { a2 = a1; i2 = i1; }
                else                                   { a2 = o2; i2 = oi2; }
                a1 = o1; i1 = oi1;
            } else {
                if (o1 > a2 || (o1 == a2 && oi1 < i2)) { a2 = o1; i2 = oi1; }
            }
        }
        const float s1 = __shfl(sc, i1);   // bitwise == scores entries
        const float s2 = __shfl(sc, i2);
        if (lane == 0) {
            out[(size_t)r2 * TOPK + 0]  = s1;
            out[(size_t)r2 * TOPK + 1]  = s2;
            iout[(size_t)r2 * TOPK + 0] = (float)i1;
            iout[(size_t)r2 * TOPK + 1] = (float)i2;
        }
    }
}

extern "C" void kernel_launch(void* const* d_in, const int* in_sizes, int n_in,
                              void* d_out, int out_size, void* d_ws, size_t ws_size,
                              hipStream_t stream)
{
    const float* x     = (const float*)d_in[0];
    const float* W     = (const float*)d_in[1];
    const float* bias  = (const float*)d_in[2];
    const float* noise = (const float*)d_in[3];
    float* out = (float*)d_out;
    (void)in_sizes; (void)n_in; (void)out_size; (void)ws_size;

    _Float16* wint = (_Float16*)d_ws;            // 512 KB interleaved hi|lo

    hipLaunchKernelGGL(wsplit_kernel, dim3(NEXP), dim3(256), 0, stream, W, wint);
    hipLaunchKernelGGL(router_mfma, dim3(BS_TOT / RPB), dim3(512), 0, stream,
                       x, wint, bias, noise, out);
}